// Round 1
// 2586.706 us; speedup vs baseline: 1.0736x; 1.0736x over previous
//
#include <hip/hip_runtime.h>
#include <hip/hip_bf16.h>
#include <math.h>

// B=2 T=1024 HID=2048 H=16 D=128 DV=128 R=4 CONV=4
// Inputs fp32, output fp32 (R6-validated). Staging bf16, state fp32.
// R8: scan re-partitioned to 1 column/wave (64 lanes over d=128, 2 d/lane),
// 1024 blocks x 256 threads = 4096 waves = 4 waves/SIMD (was 1/SIMD).
// red64 = validated red16 DPP ladder + shfl_xor 16/32. All other kernels
// byte-identical to the R7-validated versions.

typedef unsigned short ushort_t;
typedef __attribute__((ext_vector_type(8))) short bf16x8;
typedef __attribute__((ext_vector_type(4))) float f32x4;

__device__ __forceinline__ unsigned short f2bf(float f) {
  unsigned u = __float_as_uint(f);
  unsigned r = (u + 0x7FFFu + ((u >> 16) & 1u)) >> 16;  // RNE
  return (unsigned short)r;
}
__device__ __forceinline__ float bf2f(unsigned short u) {
  return __uint_as_float(((unsigned)u) << 16);
}
__device__ __forceinline__ float sigmoidf(float x) { return 1.f / (1.f + expf(-x)); }
__device__ __forceinline__ float softplusf(float x) {
  return (x > 20.f) ? x : log1pf(expf(x));
}
__device__ __forceinline__ void store1(float* p, float v) { *p = v; }
__device__ __forceinline__ void store1(unsigned short* p, float v) { *p = f2bf(v); }

// ---------------------------------------------------------------------------
// MFMA GEMM (NT): Y[m,n] = sum_k X[m,k]*W[n,k]. X:(M,K) f32, W:(N,K) f32.
// fp32 -> bf16 conversion during LDS staging. 128x128 tile, 256 thr (4 waves,
// 2x2 wave grid, 4x4 16x16 frags/wave), BK=32. LDS rows padded to 40 bf16.
// M, K multiples of 128/32; N arbitrary (guarded).
// ---------------------------------------------------------------------------
template <typename OutT>
__global__ __launch_bounds__(256) void gemm_mfma(const float* __restrict__ A,
                                                 const float* __restrict__ B,
                                                 OutT* __restrict__ Y,
                                                 int M, int N, int K) {
  __shared__ __attribute__((aligned(16))) unsigned short As[128 * 40];
  __shared__ __attribute__((aligned(16))) unsigned short Bs[128 * 40];
  const int tid = threadIdx.x;
  const int lane = tid & 63;
  const int wave = tid >> 6;
  const int quad = lane >> 4;
  const int l16 = lane & 15;
  const int wm = wave >> 1;   // 0..1
  const int wn = wave & 1;    // 0..1
  const int n0 = blockIdx.x * 128;
  const int m0 = blockIdx.y * 128;

  f32x4 acc[4][4];
#pragma unroll
  for (int i = 0; i < 4; ++i)
#pragma unroll
    for (int j = 0; j < 4; ++j) acc[i][j] = (f32x4){0.f, 0.f, 0.f, 0.f};

  for (int k0 = 0; k0 < K; k0 += 32) {
    __syncthreads();
    // stage A tile (128 x 32): 512 8-element units, 2 per thread
#pragma unroll
    for (int u = tid; u < 512; u += 256) {
      int m = u >> 2, c = u & 3;
      const float* src = A + (size_t)(m0 + m) * K + k0 + c * 8;
      float4 a0 = *(const float4*)(src);
      float4 a1 = *(const float4*)(src + 4);
      *(ushort4*)&As[m * 40 + c * 8] =
          make_ushort4(f2bf(a0.x), f2bf(a0.y), f2bf(a0.z), f2bf(a0.w));
      *(ushort4*)&As[m * 40 + c * 8 + 4] =
          make_ushort4(f2bf(a1.x), f2bf(a1.y), f2bf(a1.z), f2bf(a1.w));
    }
    // stage B tile (128 x 32), rows >= N zero-filled
#pragma unroll
    for (int u = tid; u < 512; u += 256) {
      int n = u >> 2, c = u & 3;
      float4 b0 = make_float4(0.f, 0.f, 0.f, 0.f);
      float4 b1 = b0;
      if (n0 + n < N) {
        const float* src = B + (size_t)(n0 + n) * K + k0 + c * 8;
        b0 = *(const float4*)(src);
        b1 = *(const float4*)(src + 4);
      }
      *(ushort4*)&Bs[n * 40 + c * 8] =
          make_ushort4(f2bf(b0.x), f2bf(b0.y), f2bf(b0.z), f2bf(b0.w));
      *(ushort4*)&Bs[n * 40 + c * 8 + 4] =
          make_ushort4(f2bf(b1.x), f2bf(b1.y), f2bf(b1.z), f2bf(b1.w));
    }
    __syncthreads();

    bf16x8 av[4], bv[4];
#pragma unroll
    for (int i = 0; i < 4; ++i)
      av[i] = *(const bf16x8*)&As[(wm * 64 + i * 16 + l16) * 40 + quad * 8];
#pragma unroll
    for (int j = 0; j < 4; ++j)
      bv[j] = *(const bf16x8*)&Bs[(wn * 64 + j * 16 + l16) * 40 + quad * 8];
#pragma unroll
    for (int i = 0; i < 4; ++i)
#pragma unroll
      for (int j = 0; j < 4; ++j)
        acc[i][j] = __builtin_amdgcn_mfma_f32_16x16x32_bf16(av[i], bv[j], acc[i][j], 0, 0, 0);
  }

  // epilogue: D[row=quad*4+reg][col=l16] per 16x16 tile
#pragma unroll
  for (int i = 0; i < 4; ++i)
#pragma unroll
    for (int j = 0; j < 4; ++j) {
      int rr = m0 + wm * 64 + i * 16 + quad * 4;
      int cc = n0 + wn * 64 + j * 16 + l16;
      if (cc < N) {
#pragma unroll
        for (int r = 0; r < 4; ++r)
          store1(Y + (size_t)(rr + r) * N + cc, acc[i][j][r]);
      }
    }
}

// ---------------------------------------------------------------------------
// Depthwise causal conv (K=4) + silu — scalar (R6-validated).
// ---------------------------------------------------------------------------
__global__ __launch_bounds__(256) void conv_silu_s(const unsigned short* __restrict__ X,
                                                   const float* __restrict__ Wc,
                                                   unsigned short* __restrict__ Y,
                                                   int C, int total) {
  int idx = blockIdx.x * 256 + threadIdx.x;
  if (idx >= total) return;
  int c = idx % C;
  int m = idx / C;
  int t = m & 1023;
  const float* w = Wc + (size_t)c * 4;
  float acc = w[3] * bf2f(X[idx]);
  if (t >= 1) acc = fmaf(w[2], bf2f(X[idx - C]), acc);
  if (t >= 2) acc = fmaf(w[1], bf2f(X[idx - 2 * C]), acc);
  if (t >= 3) acc = fmaf(w[0], bf2f(X[idx - 3 * C]), acc);
  Y[idx] = f2bf(acc * sigmoidf(acc));
}

// ---------------------------------------------------------------------------
// l2norm rows of 128 (bf16, in-place) — R6-validated.
// ---------------------------------------------------------------------------
__global__ __launch_bounds__(256) void l2norm_bf16(unsigned short* __restrict__ X,
                                                   int rows, float post) {
  int row = blockIdx.x * 4 + (threadIdx.x >> 6);
  int lane = threadIdx.x & 63;
  if (row >= rows) return;
  unsigned short* p = X + (size_t)row * 128;
  float a = bf2f(p[lane]), b = bf2f(p[lane + 64]);
  float ss = fmaf(a, a, b * b);
#pragma unroll
  for (int m = 32; m; m >>= 1) ss += __shfl_xor(ss, m);
  float sc = rsqrtf(ss + 1e-6f) * post;
  p[lane] = f2bf(a * sc);
  p[lane + 64] = f2bf(b * sc);
}

// ---------------------------------------------------------------------------
// decay in-place (R6-validated).
// ---------------------------------------------------------------------------
__global__ __launch_bounds__(256) void decay_ip(float* __restrict__ G,
                                                const float* __restrict__ alog,
                                                const float* __restrict__ dtb,
                                                int total) {
  int idx = blockIdx.x * 256 + threadIdx.x;
  if (idx >= total) return;
  int n = idx & 2047;
  float A = expf(alog[n >> 7]);
  float x = G[idx] + dtb[n];
  G[idx] = expf(-A * softplusf(x));
}

__global__ __launch_bounds__(256) void sigmoid_ip(float* __restrict__ G, int total) {
  int idx = blockIdx.x * 256 + threadIdx.x;
  if (idx < total) G[idx] = sigmoidf(G[idx]);
}

// ---------------------------------------------------------------------------
// Recurrent scan v3 — 1 column per wave, 64 lanes over d=128 (2 d per lane).
// 1024 blocks x 256 threads (4 waves/block, wave = column within 4-col group).
// 4096 waves total = 16 waves/CU = 4 waves/SIMD (was 1/SIMD in v2) so the
// serial dependence chain (decay -> k.S reduce -> cc -> S update) hides
// across co-resident waves. Reduction over 64 lanes: validated 16-lane DPP
// ladder (xor1=0xB1, xor2=0x4E, half_mirror=0x141, mirror=0x140) then
// shfl_xor 16 and 32.
// ---------------------------------------------------------------------------
template <int CTRL>
__device__ __forceinline__ float dppadd(float x) {
  int y = __builtin_amdgcn_update_dpp(0, __float_as_int(x), CTRL, 0xF, 0xF, true);
  return x + __int_as_float(y);
}
__device__ __forceinline__ float red64(float x) {
  x = dppadd<0xB1>(x);
  x = dppadd<0x4E>(x);
  x = dppadd<0x141>(x);
  x = dppadd<0x140>(x);
  x += __shfl_xor(x, 16);
  x += __shfl_xor(x, 32);
  return x;
}

struct Pref {
  ushort2 k[4];        // k[j] at d0, d0+1
  ushort2 q;
  float2 d;
  float4 beta;
  unsigned short v[4]; // v[j] at column col (wave-uniform)
};

__global__ __launch_bounds__(256) void scan_kernel3(
    const unsigned short* __restrict__ Qn, const unsigned short* __restrict__ Kn,
    const unsigned short* __restrict__ Vb, const float* __restrict__ Dec,
    const float* __restrict__ BetaS, const float* __restrict__ ml,
    const float* __restrict__ alog, const float* __restrict__ dtb,
    float* __restrict__ O) {
  const int blk = blockIdx.x;        // 1024
  const int cq = blk & 31;           // 32 groups of 4 columns
  const int bh = blk >> 5;           // 0..31
  const int h = bh & 15;
  const int b = bh >> 4;
  const int wave = threadIdx.x >> 6; // 0..3 -> column within group
  const int lane = threadIdx.x & 63;
  const int col = cq * 4 + wave;
  const int d0 = lane * 2;

  const float A = expf(alog[h]);
  const float df0 = expf(-A * softplusf(-10000.f + dtb[h * 128 + d0]));
  const float df1 = expf(-A * softplusf(-10000.f + dtb[h * 128 + d0 + 1]));

  float wj[4];
  {
    float l0 = ml[h * 4 + 0], l1 = ml[h * 4 + 1];
    float l2 = ml[h * 4 + 2], l3 = ml[h * 4 + 3];
    float mx = fmaxf(fmaxf(l0, l1), fmaxf(l2, l3));
    float e0 = expf(l0 - mx), e1 = expf(l1 - mx);
    float e2 = expf(l2 - mx), e3 = expf(l3 - mx);
    float inv = 1.f / (e0 + e1 + e2 + e3);
    wj[0] = e0 * inv; wj[1] = e1 * inv; wj[2] = e2 * inv; wj[3] = e3 * inv;
  }

  float S0 = 0.f, S1 = 0.f;

  auto LD = [&](int t, Pref& P) {
    const size_t base = ((size_t)(b * 1024 + t) * 16 + h);
    const unsigned short* kp = Kn + base * 512 + d0;
    const unsigned short* vp = Vb + base * 512 + col;
#pragma unroll
    for (int j = 0; j < 4; ++j) {
      P.k[j] = *(const ushort2*)(kp + j * 128);
      P.v[j] = vp[j * 128];
    }
    P.q = *(const ushort2*)(Qn + base * 128 + d0);
    P.d = *(const float2*)(Dec + base * 128 + d0);
    P.beta = *(const float4*)(BetaS + base * 4);
  };

  auto STEP = [&](const Pref& P, int t) {
    const float qf0 = bf2f(P.q.x), qf1 = bf2f(P.q.y);
    float o_acc = 0.f;
    const float bc[4] = {P.beta.x, P.beta.y, P.beta.z, P.beta.w};
#pragma unroll
    for (int j = 0; j < 4; ++j) {
      const float kf0 = bf2f(P.k[j].x), kf1 = bf2f(P.k[j].y);
      const float dd0 = (j == 0) ? P.d.x : df0;
      const float dd1 = (j == 0) ? P.d.y : df1;
      S0 *= dd0;
      S1 *= dd1;
      float u = red64(fmaf(kf0, S0, kf1 * S1));
      float cc = bc[j] * (bf2f(P.v[j]) - u);
      S0 = fmaf(cc, kf0, S0);
      S1 = fmaf(cc, kf1, S1);
      o_acc = fmaf(wj[j], fmaf(qf0, S0, qf1 * S1), o_acc);
    }
    o_acc = red64(o_acc);
    if (lane == 0) {
      const size_t base = ((size_t)(b * 1024 + t) * 16 + h);
      O[base * 128 + col] = o_acc;
    }
  };

  Pref P0, P1;
  LD(0, P0);
  for (int t = 0; t < 1024; t += 2) {
    LD(t + 1, P1);
    STEP(P0, t);
    if (t + 2 < 1024) LD(t + 2, P0);
    STEP(P1, t + 1);
  }
}

// ---------------------------------------------------------------------------
// RMS-norm * o_norm_w * sigmoid(gate + g2_b), in-place on O(f32) — R6-validated.
// ---------------------------------------------------------------------------
__global__ __launch_bounds__(256) void norm_gate(float* __restrict__ O,
                                                 const unsigned short* __restrict__ G,
                                                 const float* __restrict__ g2b,
                                                 const float* __restrict__ onw,
                                                 int rows) {
  int row = blockIdx.x * 4 + (threadIdx.x >> 6);
  int lane = threadIdx.x & 63;
  if (row >= rows) return;
  float* p = O + (size_t)row * 128;
  int m = row >> 4, h = row & 15;
  const unsigned short* gp = G + (size_t)m * 2048 + h * 128;
  const float* gb = g2b + h * 128;
  float a = p[lane], bv = p[lane + 64];
  float ss = fmaf(a, a, bv * bv);
#pragma unroll
  for (int k = 32; k; k >>= 1) ss += __shfl_xor(ss, k);
  float sc = rsqrtf(ss * (1.f / 128.f) + 1e-5f);
  float ga = sigmoidf(bf2f(gp[lane]) + gb[lane]);
  float gbv = sigmoidf(bf2f(gp[lane + 64]) + gb[lane + 64]);
  p[lane] = a * sc * onw[lane] * ga;
  p[lane + 64] = bv * sc * onw[lane + 64] * gbv;
}

// ---------------------------------------------------------------------------
extern "C" void kernel_launch(void* const* d_in, const int* in_sizes, int n_in,
                              void* d_out, int out_size, void* d_ws, size_t ws_size,
                              hipStream_t stream) {
  const float* x    = (const float*)d_in[0];
  const float* qw   = (const float*)d_in[1];
  const float* kw   = (const float*)d_in[2];
  const float* vw   = (const float*)d_in[3];
  const float* qcw  = (const float*)d_in[4];
  const float* kcw  = (const float*)d_in[5];
  const float* vcw  = (const float*)d_in[6];
  const float* f1w  = (const float*)d_in[7];
  const float* f2w  = (const float*)d_in[8];
  const float* bw   = (const float*)d_in[9];
  const float* ml   = (const float*)d_in[10];
  const float* alog = (const float*)d_in[11];
  const float* dtb  = (const float*)d_in[12];
  const float* g1w  = (const float*)d_in[13];
  const float* g2w  = (const float*)d_in[14];
  const float* g2b  = (const float*)d_in[15];
  const float* onw  = (const float*)d_in[16];
  const float* ow   = (const float*)d_in[17];
  float* out = (float*)d_out;  // fp32 output

  // workspace carve — peak 120 MiB (R6-validated layout).
  char* w8 = (char*)d_ws;
  unsigned short* P    = (unsigned short*)(w8);               // [0, 32M) staging
  float*          dec  = (float*)(w8);                        // [0, 16M)
  unsigned short* gate = (unsigned short*)(w8 + 16777216);    // 8 MB
  float*          beta = (float*)(w8 + 25165824);             // 512 KB
  float*          g1t  = (float*)(w8 + 25690112);             // 1 MB
  unsigned short* Kc   = (unsigned short*)(w8 + 33554432);    // 32 MB
  unsigned short* Vc   = (unsigned short*)(w8 + 67108864);    // 32 MB
  unsigned short* Qc   = (unsigned short*)(w8 + 100663296);   // 8 MB
  float*          o    = (float*)(w8 + 109051904);            // 16 MB (ends 120 MiB)
  (void)ws_size;

  const int M = 2048;
  dim3 blk(256);

  // ---- phase 1: projections (MFMA) + conv ----
  gemm_mfma<unsigned short><<<dim3(64, 16), blk, 0, stream>>>(x, kw, P, M, 8192, 2048);
  conv_silu_s<<<65536, blk, 0, stream>>>(P, kcw, Kc, 8192, 16777216);
  gemm_mfma<unsigned short><<<dim3(64, 16), blk, 0, stream>>>(x, vw, P, M, 8192, 2048);
  conv_silu_s<<<65536, blk, 0, stream>>>(P, vcw, Vc, 8192, 16777216);
  gemm_mfma<unsigned short><<<dim3(16, 16), blk, 0, stream>>>(x, qw, P, M, 2048, 2048);
  conv_silu_s<<<16384, blk, 0, stream>>>(P, qcw, Qc, 2048, 4194304);

  // ---- phase 2: small projections (P region now dead) ----
  gemm_mfma<float><<<dim3(1, 16), blk, 0, stream>>>(x, f1w, g1t, M, 128, 2048);
  gemm_mfma<float><<<dim3(16, 16), blk, 0, stream>>>(g1t, f2w, dec, M, 2048, 128);
  decay_ip<<<16384, blk, 0, stream>>>(dec, alog, dtb, 4194304);

  gemm_mfma<float><<<dim3(1, 16), blk, 0, stream>>>(x, bw, beta, M, 64, 2048);
  sigmoid_ip<<<512, blk, 0, stream>>>(beta, 131072);

  gemm_mfma<float><<<dim3(1, 16), blk, 0, stream>>>(x, g1w, g1t, M, 128, 2048);
  gemm_mfma<unsigned short><<<dim3(16, 16), blk, 0, stream>>>(g1t, g2w, gate, M, 2048, 128);

  // ---- l2 norms (in-place bf16) ----
  l2norm_bf16<<<8192, blk, 0, stream>>>(Qc, 32768, 0.08838834764831845f);
  l2norm_bf16<<<32768, blk, 0, stream>>>(Kc, 131072, 1.0f);

  // ---- recurrent scan (1 column/wave, 4 waves/SIMD) ----
  scan_kernel3<<<1024, dim3(256), 0, stream>>>(Qc, Kc, Vc, dec, beta, ml, alog, dtb, o);

  // ---- RMS-norm + gate ----
  norm_gate<<<8192, blk, 0, stream>>>(o, gate, g2b, onw, 32768);

  // ---- final projection -> fp32 out ----
  gemm_mfma<float><<<dim3(16, 16), blk, 0, stream>>>(o, ow, out, M, 2048, 2048);
}

// Round 2
// 2475.692 us; speedup vs baseline: 1.1218x; 1.0448x over previous
//
#include <hip/hip_runtime.h>
#include <hip/hip_bf16.h>
#include <math.h>

// B=2 T=1024 HID=2048 H=16 D=128 DV=128 R=4 CONV=4
// Inputs fp32, output fp32 (R6-validated). Staging bf16, state fp32.
// R9: scan reduce rebuilt as all-DPP ladder + v_readlane broadcast (no
// ds_bpermute / lgkmcnt on the critical path). Ladder: xor1(0xB1),
// xor2(0x4E), half_mirror(0x141), mirror(0x140) -> 16-lane row sums
// (R6-validated), then row_bcast15(0x142), row_bcast31(0x143) -> total in
// lane 63, broadcast via v_readlane_b32 (SGPR, uniform). All other kernels
// byte-identical to the R8-validated versions.

typedef unsigned short ushort_t;
typedef __attribute__((ext_vector_type(8))) short bf16x8;
typedef __attribute__((ext_vector_type(4))) float f32x4;

__device__ __forceinline__ unsigned short f2bf(float f) {
  unsigned u = __float_as_uint(f);
  unsigned r = (u + 0x7FFFu + ((u >> 16) & 1u)) >> 16;  // RNE
  return (unsigned short)r;
}
__device__ __forceinline__ float bf2f(unsigned short u) {
  return __uint_as_float(((unsigned)u) << 16);
}
__device__ __forceinline__ float sigmoidf(float x) { return 1.f / (1.f + expf(-x)); }
__device__ __forceinline__ float softplusf(float x) {
  return (x > 20.f) ? x : log1pf(expf(x));
}
__device__ __forceinline__ void store1(float* p, float v) { *p = v; }
__device__ __forceinline__ void store1(unsigned short* p, float v) { *p = f2bf(v); }

// ---------------------------------------------------------------------------
// MFMA GEMM (NT): Y[m,n] = sum_k X[m,k]*W[n,k]. X:(M,K) f32, W:(N,K) f32.
// fp32 -> bf16 conversion during LDS staging. 128x128 tile, 256 thr (4 waves,
// 2x2 wave grid, 4x4 16x16 frags/wave), BK=32. LDS rows padded to 40 bf16.
// M, K multiples of 128/32; N arbitrary (guarded).
// ---------------------------------------------------------------------------
template <typename OutT>
__global__ __launch_bounds__(256) void gemm_mfma(const float* __restrict__ A,
                                                 const float* __restrict__ B,
                                                 OutT* __restrict__ Y,
                                                 int M, int N, int K) {
  __shared__ __attribute__((aligned(16))) unsigned short As[128 * 40];
  __shared__ __attribute__((aligned(16))) unsigned short Bs[128 * 40];
  const int tid = threadIdx.x;
  const int lane = tid & 63;
  const int wave = tid >> 6;
  const int quad = lane >> 4;
  const int l16 = lane & 15;
  const int wm = wave >> 1;   // 0..1
  const int wn = wave & 1;    // 0..1
  const int n0 = blockIdx.x * 128;
  const int m0 = blockIdx.y * 128;

  f32x4 acc[4][4];
#pragma unroll
  for (int i = 0; i < 4; ++i)
#pragma unroll
    for (int j = 0; j < 4; ++j) acc[i][j] = (f32x4){0.f, 0.f, 0.f, 0.f};

  for (int k0 = 0; k0 < K; k0 += 32) {
    __syncthreads();
    // stage A tile (128 x 32): 512 8-element units, 2 per thread
#pragma unroll
    for (int u = tid; u < 512; u += 256) {
      int m = u >> 2, c = u & 3;
      const float* src = A + (size_t)(m0 + m) * K + k0 + c * 8;
      float4 a0 = *(const float4*)(src);
      float4 a1 = *(const float4*)(src + 4);
      *(ushort4*)&As[m * 40 + c * 8] =
          make_ushort4(f2bf(a0.x), f2bf(a0.y), f2bf(a0.z), f2bf(a0.w));
      *(ushort4*)&As[m * 40 + c * 8 + 4] =
          make_ushort4(f2bf(a1.x), f2bf(a1.y), f2bf(a1.z), f2bf(a1.w));
    }
    // stage B tile (128 x 32), rows >= N zero-filled
#pragma unroll
    for (int u = tid; u < 512; u += 256) {
      int n = u >> 2, c = u & 3;
      float4 b0 = make_float4(0.f, 0.f, 0.f, 0.f);
      float4 b1 = b0;
      if (n0 + n < N) {
        const float* src = B + (size_t)(n0 + n) * K + k0 + c * 8;
        b0 = *(const float4*)(src);
        b1 = *(const float4*)(src + 4);
      }
      *(ushort4*)&Bs[n * 40 + c * 8] =
          make_ushort4(f2bf(b0.x), f2bf(b0.y), f2bf(b0.z), f2bf(b0.w));
      *(ushort4*)&Bs[n * 40 + c * 8 + 4] =
          make_ushort4(f2bf(b1.x), f2bf(b1.y), f2bf(b1.z), f2bf(b1.w));
    }
    __syncthreads();

    bf16x8 av[4], bv[4];
#pragma unroll
    for (int i = 0; i < 4; ++i)
      av[i] = *(const bf16x8*)&As[(wm * 64 + i * 16 + l16) * 40 + quad * 8];
#pragma unroll
    for (int j = 0; j < 4; ++j)
      bv[j] = *(const bf16x8*)&Bs[(wn * 64 + j * 16 + l16) * 40 + quad * 8];
#pragma unroll
    for (int i = 0; i < 4; ++i)
#pragma unroll
      for (int j = 0; j < 4; ++j)
        acc[i][j] = __builtin_amdgcn_mfma_f32_16x16x32_bf16(av[i], bv[j], acc[i][j], 0, 0, 0);
  }

  // epilogue: D[row=quad*4+reg][col=l16] per 16x16 tile
#pragma unroll
  for (int i = 0; i < 4; ++i)
#pragma unroll
    for (int j = 0; j < 4; ++j) {
      int rr = m0 + wm * 64 + i * 16 + quad * 4;
      int cc = n0 + wn * 64 + j * 16 + l16;
      if (cc < N) {
#pragma unroll
        for (int r = 0; r < 4; ++r)
          store1(Y + (size_t)(rr + r) * N + cc, acc[i][j][r]);
      }
    }
}

// ---------------------------------------------------------------------------
// Depthwise causal conv (K=4) + silu — scalar (R6-validated).
// ---------------------------------------------------------------------------
__global__ __launch_bounds__(256) void conv_silu_s(const unsigned short* __restrict__ X,
                                                   const float* __restrict__ Wc,
                                                   unsigned short* __restrict__ Y,
                                                   int C, int total) {
  int idx = blockIdx.x * 256 + threadIdx.x;
  if (idx >= total) return;
  int c = idx % C;
  int m = idx / C;
  int t = m & 1023;
  const float* w = Wc + (size_t)c * 4;
  float acc = w[3] * bf2f(X[idx]);
  if (t >= 1) acc = fmaf(w[2], bf2f(X[idx - C]), acc);
  if (t >= 2) acc = fmaf(w[1], bf2f(X[idx - 2 * C]), acc);
  if (t >= 3) acc = fmaf(w[0], bf2f(X[idx - 3 * C]), acc);
  Y[idx] = f2bf(acc * sigmoidf(acc));
}

// ---------------------------------------------------------------------------
// l2norm rows of 128 (bf16, in-place) — R6-validated.
// ---------------------------------------------------------------------------
__global__ __launch_bounds__(256) void l2norm_bf16(unsigned short* __restrict__ X,
                                                   int rows, float post) {
  int row = blockIdx.x * 4 + (threadIdx.x >> 6);
  int lane = threadIdx.x & 63;
  if (row >= rows) return;
  unsigned short* p = X + (size_t)row * 128;
  float a = bf2f(p[lane]), b = bf2f(p[lane + 64]);
  float ss = fmaf(a, a, b * b);
#pragma unroll
  for (int m = 32; m; m >>= 1) ss += __shfl_xor(ss, m);
  float sc = rsqrtf(ss + 1e-6f) * post;
  p[lane] = f2bf(a * sc);
  p[lane + 64] = f2bf(b * sc);
}

// ---------------------------------------------------------------------------
// decay in-place (R6-validated).
// ---------------------------------------------------------------------------
__global__ __launch_bounds__(256) void decay_ip(float* __restrict__ G,
                                                const float* __restrict__ alog,
                                                const float* __restrict__ dtb,
                                                int total) {
  int idx = blockIdx.x * 256 + threadIdx.x;
  if (idx >= total) return;
  int n = idx & 2047;
  float A = expf(alog[n >> 7]);
  float x = G[idx] + dtb[n];
  G[idx] = expf(-A * softplusf(x));
}

__global__ __launch_bounds__(256) void sigmoid_ip(float* __restrict__ G, int total) {
  int idx = blockIdx.x * 256 + threadIdx.x;
  if (idx < total) G[idx] = sigmoidf(G[idx]);
}

// ---------------------------------------------------------------------------
// Recurrent scan v4 — 1 column per wave, 64 lanes over d=128 (2 d per lane).
// 1024 blocks x 256 threads; 4096 waves = 4 waves/SIMD.
// Reduction: all-DPP ladder, zero DS ops on the dependence chain:
//   xor1 = quad_perm[1,0,3,2] (0xB1), xor2 = quad_perm[2,3,0,1] (0x4E),
//   half_mirror (0x141), mirror (0x140)  -> each 16-lane row holds row sum,
//   row_bcast15 (0x142): row r+1 += row r (src lanes 15/31/47),
//   row_bcast31 (0x143): rows 2,3 += lane31 (rows 0+1 sum),
//   -> lane 63 holds the 64-lane total; v_readlane_b32 broadcasts via SGPR.
// bound_ctrl=1 so lanes without a DPP source add 0 (keep their value).
// ---------------------------------------------------------------------------
template <int CTRL>
__device__ __forceinline__ float dppadd(float x) {
  int y = __builtin_amdgcn_update_dpp(0, __float_as_int(x), CTRL, 0xF, 0xF, true);
  return x + __int_as_float(y);
}
__device__ __forceinline__ float red64(float x) {
  x = dppadd<0xB1>(x);
  x = dppadd<0x4E>(x);
  x = dppadd<0x141>(x);
  x = dppadd<0x140>(x);
  x = dppadd<0x142>(x);   // row_bcast15
  x = dppadd<0x143>(x);   // row_bcast31 -> lane 63 = total
  return __int_as_float(__builtin_amdgcn_readlane(__float_as_int(x), 63));
}

struct Pref {
  ushort2 k[4];        // k[j] at d0, d0+1
  ushort2 q;
  float2 d;
  float4 beta;
  unsigned short v[4]; // v[j] at column col (wave-uniform)
};

__global__ __launch_bounds__(256) void scan_kernel4(
    const unsigned short* __restrict__ Qn, const unsigned short* __restrict__ Kn,
    const unsigned short* __restrict__ Vb, const float* __restrict__ Dec,
    const float* __restrict__ BetaS, const float* __restrict__ ml,
    const float* __restrict__ alog, const float* __restrict__ dtb,
    float* __restrict__ O) {
  const int blk = blockIdx.x;        // 1024
  const int cq = blk & 31;           // 32 groups of 4 columns
  const int bh = blk >> 5;           // 0..31
  const int h = bh & 15;
  const int b = bh >> 4;
  const int wave = threadIdx.x >> 6; // 0..3 -> column within group
  const int lane = threadIdx.x & 63;
  const int col = cq * 4 + wave;
  const int d0 = lane * 2;

  const float A = expf(alog[h]);
  const float df0 = expf(-A * softplusf(-10000.f + dtb[h * 128 + d0]));
  const float df1 = expf(-A * softplusf(-10000.f + dtb[h * 128 + d0 + 1]));

  float wj[4];
  {
    float l0 = ml[h * 4 + 0], l1 = ml[h * 4 + 1];
    float l2 = ml[h * 4 + 2], l3 = ml[h * 4 + 3];
    float mx = fmaxf(fmaxf(l0, l1), fmaxf(l2, l3));
    float e0 = expf(l0 - mx), e1 = expf(l1 - mx);
    float e2 = expf(l2 - mx), e3 = expf(l3 - mx);
    float inv = 1.f / (e0 + e1 + e2 + e3);
    wj[0] = e0 * inv; wj[1] = e1 * inv; wj[2] = e2 * inv; wj[3] = e3 * inv;
  }

  float S0 = 0.f, S1 = 0.f;

  auto LD = [&](int t, Pref& P) {
    const size_t base = ((size_t)(b * 1024 + t) * 16 + h);
    const unsigned short* kp = Kn + base * 512 + d0;
    const unsigned short* vp = Vb + base * 512 + col;
#pragma unroll
    for (int j = 0; j < 4; ++j) {
      P.k[j] = *(const ushort2*)(kp + j * 128);
      P.v[j] = vp[j * 128];
    }
    P.q = *(const ushort2*)(Qn + base * 128 + d0);
    P.d = *(const float2*)(Dec + base * 128 + d0);
    P.beta = *(const float4*)(BetaS + base * 4);
  };

  auto STEP = [&](const Pref& P, int t) {
    const float qf0 = bf2f(P.q.x), qf1 = bf2f(P.q.y);
    float o_acc = 0.f;
    const float bc[4] = {P.beta.x, P.beta.y, P.beta.z, P.beta.w};
#pragma unroll
    for (int j = 0; j < 4; ++j) {
      const float kf0 = bf2f(P.k[j].x), kf1 = bf2f(P.k[j].y);
      const float dd0 = (j == 0) ? P.d.x : df0;
      const float dd1 = (j == 0) ? P.d.y : df1;
      S0 *= dd0;
      S1 *= dd1;
      float u = red64(fmaf(kf0, S0, kf1 * S1));
      float cc = bc[j] * (bf2f(P.v[j]) - u);
      S0 = fmaf(cc, kf0, S0);
      S1 = fmaf(cc, kf1, S1);
      o_acc = fmaf(wj[j], fmaf(qf0, S0, qf1 * S1), o_acc);
    }
    o_acc = red64(o_acc);
    if (lane == 0) {
      const size_t base = ((size_t)(b * 1024 + t) * 16 + h);
      O[base * 128 + col] = o_acc;
    }
  };

  Pref P0, P1;
  LD(0, P0);
  for (int t = 0; t < 1024; t += 2) {
    LD(t + 1, P1);
    STEP(P0, t);
    if (t + 2 < 1024) LD(t + 2, P0);
    STEP(P1, t + 1);
  }
}

// ---------------------------------------------------------------------------
// RMS-norm * o_norm_w * sigmoid(gate + g2_b), in-place on O(f32) — R6-validated.
// ---------------------------------------------------------------------------
__global__ __launch_bounds__(256) void norm_gate(float* __restrict__ O,
                                                 const unsigned short* __restrict__ G,
                                                 const float* __restrict__ g2b,
                                                 const float* __restrict__ onw,
                                                 int rows) {
  int row = blockIdx.x * 4 + (threadIdx.x >> 6);
  int lane = threadIdx.x & 63;
  if (row >= rows) return;
  float* p = O + (size_t)row * 128;
  int m = row >> 4, h = row & 15;
  const unsigned short* gp = G + (size_t)m * 2048 + h * 128;
  const float* gb = g2b + h * 128;
  float a = p[lane], bv = p[lane + 64];
  float ss = fmaf(a, a, bv * bv);
#pragma unroll
  for (int k = 32; k; k >>= 1) ss += __shfl_xor(ss, k);
  float sc = rsqrtf(ss * (1.f / 128.f) + 1e-5f);
  float ga = sigmoidf(bf2f(gp[lane]) + gb[lane]);
  float gbv = sigmoidf(bf2f(gp[lane + 64]) + gb[lane + 64]);
  p[lane] = a * sc * onw[lane] * ga;
  p[lane + 64] = bv * sc * onw[lane + 64] * gbv;
}

// ---------------------------------------------------------------------------
extern "C" void kernel_launch(void* const* d_in, const int* in_sizes, int n_in,
                              void* d_out, int out_size, void* d_ws, size_t ws_size,
                              hipStream_t stream) {
  const float* x    = (const float*)d_in[0];
  const float* qw   = (const float*)d_in[1];
  const float* kw   = (const float*)d_in[2];
  const float* vw   = (const float*)d_in[3];
  const float* qcw  = (const float*)d_in[4];
  const float* kcw  = (const float*)d_in[5];
  const float* vcw  = (const float*)d_in[6];
  const float* f1w  = (const float*)d_in[7];
  const float* f2w  = (const float*)d_in[8];
  const float* bw   = (const float*)d_in[9];
  const float* ml   = (const float*)d_in[10];
  const float* alog = (const float*)d_in[11];
  const float* dtb  = (const float*)d_in[12];
  const float* g1w  = (const float*)d_in[13];
  const float* g2w  = (const float*)d_in[14];
  const float* g2b  = (const float*)d_in[15];
  const float* onw  = (const float*)d_in[16];
  const float* ow   = (const float*)d_in[17];
  float* out = (float*)d_out;  // fp32 output

  // workspace carve — peak 120 MiB (R6-validated layout).
  char* w8 = (char*)d_ws;
  unsigned short* P    = (unsigned short*)(w8);               // [0, 32M) staging
  float*          dec  = (float*)(w8);                        // [0, 16M)
  unsigned short* gate = (unsigned short*)(w8 + 16777216);    // 8 MB
  float*          beta = (float*)(w8 + 25165824);             // 512 KB
  float*          g1t  = (float*)(w8 + 25690112);             // 1 MB
  unsigned short* Kc   = (unsigned short*)(w8 + 33554432);    // 32 MB
  unsigned short* Vc   = (unsigned short*)(w8 + 67108864);    // 32 MB
  unsigned short* Qc   = (unsigned short*)(w8 + 100663296);   // 8 MB
  float*          o    = (float*)(w8 + 109051904);            // 16 MB (ends 120 MiB)
  (void)ws_size;

  const int M = 2048;
  dim3 blk(256);

  // ---- phase 1: projections (MFMA) + conv ----
  gemm_mfma<unsigned short><<<dim3(64, 16), blk, 0, stream>>>(x, kw, P, M, 8192, 2048);
  conv_silu_s<<<65536, blk, 0, stream>>>(P, kcw, Kc, 8192, 16777216);
  gemm_mfma<unsigned short><<<dim3(64, 16), blk, 0, stream>>>(x, vw, P, M, 8192, 2048);
  conv_silu_s<<<65536, blk, 0, stream>>>(P, vcw, Vc, 8192, 16777216);
  gemm_mfma<unsigned short><<<dim3(16, 16), blk, 0, stream>>>(x, qw, P, M, 2048, 2048);
  conv_silu_s<<<16384, blk, 0, stream>>>(P, qcw, Qc, 2048, 4194304);

  // ---- phase 2: small projections (P region now dead) ----
  gemm_mfma<float><<<dim3(1, 16), blk, 0, stream>>>(x, f1w, g1t, M, 128, 2048);
  gemm_mfma<float><<<dim3(16, 16), blk, 0, stream>>>(g1t, f2w, dec, M, 2048, 128);
  decay_ip<<<16384, blk, 0, stream>>>(dec, alog, dtb, 4194304);

  gemm_mfma<float><<<dim3(1, 16), blk, 0, stream>>>(x, bw, beta, M, 64, 2048);
  sigmoid_ip<<<512, blk, 0, stream>>>(beta, 131072);

  gemm_mfma<float><<<dim3(1, 16), blk, 0, stream>>>(x, g1w, g1t, M, 128, 2048);
  gemm_mfma<unsigned short><<<dim3(16, 16), blk, 0, stream>>>(g1t, g2w, gate, M, 2048, 128);

  // ---- l2 norms (in-place bf16) ----
  l2norm_bf16<<<8192, blk, 0, stream>>>(Qc, 32768, 0.08838834764831845f);
  l2norm_bf16<<<32768, blk, 0, stream>>>(Kc, 131072, 1.0f);

  // ---- recurrent scan (all-DPP reduce, 4 waves/SIMD) ----
  scan_kernel4<<<1024, dim3(256), 0, stream>>>(Qc, Kc, Vc, dec, beta, ml, alog, dtb, o);

  // ---- RMS-norm + gate ----
  norm_gate<<<8192, blk, 0, stream>>>(o, gate, g2b, onw, 32768);

  // ---- final projection -> fp32 out ----
  gemm_mfma<float><<<dim3(16, 16), blk, 0, stream>>>(o, ow, out, M, 2048, 2048);
}